// Round 4
// baseline (212.227 us; speedup 1.0000x reference)
//
#include <hip/hip_runtime.h>
#include <hip/hip_fp16.h>
#include <math.h>

#define NH 16
#define NWL 16

typedef _Float16 half8 __attribute__((ext_vector_type(8)));
typedef _Float16 half4 __attribute__((ext_vector_type(4)));
typedef float f32x4 __attribute__((ext_vector_type(4)));

// ---------------------------------------------------------------------------
// cast x (fp32 -> f16), 8 elems/thread
// ---------------------------------------------------------------------------
__global__ __launch_bounds__(256)
void cast_x_k(const float* __restrict__ X, _Float16* __restrict__ Xh)
{
    const int i = (blockIdx.x * 256 + threadIdx.x) * 8;
    float4 v0 = *(const float4*)&X[i];
    float4 v1 = *(const float4*)&X[i + 4];
    half8 o;
    o[0] = (_Float16)v0.x; o[1] = (_Float16)v0.y; o[2] = (_Float16)v0.z; o[3] = (_Float16)v0.w;
    o[4] = (_Float16)v1.x; o[5] = (_Float16)v1.y; o[6] = (_Float16)v1.z; o[7] = (_Float16)v1.w;
    *(half8*)&Xh[i] = o;
}

// ---------------------------------------------------------------------------
// cast + transpose W[e][f] -> WT[f][e] f16, 64x64 tiles, z picks which W
// ---------------------------------------------------------------------------
__global__ __launch_bounds__(256)
void castT_w(const float* __restrict__ W0, const float* __restrict__ W1,
             const float* __restrict__ W2, const float* __restrict__ W3,
             _Float16* __restrict__ WT)
{
    const float* W = W0;
    if (blockIdx.z == 1) W = W1;
    if (blockIdx.z == 2) W = W2;
    if (blockIdx.z == 3) W = W3;
    _Float16* out = WT + ((size_t)blockIdx.z << 20);

    __shared__ float Ts[64][65];
    const int t = threadIdx.x;
    const int ebase = blockIdx.y * 64;
    const int fbase = blockIdx.x * 64;

    {
        const int r0 = (t >> 4) * 4;
        const int c0 = (t & 15) * 4;
#pragma unroll
        for (int r = 0; r < 4; ++r) {
            float4 v = *(const float4*)&W[(size_t)(ebase + r0 + r) * 1024 + fbase + c0];
            Ts[r0 + r][c0 + 0] = v.x;
            Ts[r0 + r][c0 + 1] = v.y;
            Ts[r0 + r][c0 + 2] = v.z;
            Ts[r0 + r][c0 + 3] = v.w;
        }
    }
    __syncthreads();

    const int f = t >> 2;
    const int eseg = (t & 3) * 16;
    half8 lo, hi;
#pragma unroll
    for (int j = 0; j < 8; ++j) lo[j] = (_Float16)Ts[eseg + j][f];
#pragma unroll
    for (int j = 0; j < 8; ++j) hi[j] = (_Float16)Ts[eseg + 8 + j][f];
    *(half8*)&out[(size_t)(fbase + f) * 1024 + ebase + eseg]     = lo;
    *(half8*)&out[(size_t)(fbase + f) * 1024 + ebase + eseg + 8] = hi;
}

// ---------------------------------------------------------------------------
// MFMA GEMM (f16): C[s][f] = sum_e A[s][e]*W[e][f] + bias[f]
// 64x64 tile, BK=32, 4 waves (2x2), 16x16x32_f16 frags, double-buffered LDS.
// MODE 0: fp32 out[s][f]
// MODE 1: f16 head-split: z=0,1 -> O[h][s][d]; z=2 -> transposed O[h][d][s]
// ---------------------------------------------------------------------------
template<int MODE>
__global__ __launch_bounds__(256)
void gemm_mfma(const _Float16* __restrict__ A,
               const _Float16* __restrict__ BtBase,
               const float* __restrict__ B0, const float* __restrict__ B1,
               const float* __restrict__ B2,
               void* __restrict__ O0p, void* __restrict__ O1p, void* __restrict__ O2p)
{
    const int z = blockIdx.z;
    const _Float16* Bt = BtBase + ((size_t)z << 20);
    const float* bias = B0; void* Op = O0p;
    if (z == 1) { bias = B1; Op = O1p; }
    if (z == 2) { bias = B2; Op = O2p; }

    __shared__ _Float16 As[2][64][40];
    __shared__ _Float16 Bs[2][64][40];

    const int t = threadIdx.x;
    const int lane = t & 63;
    const int w = t >> 6;
    const int w_r = w >> 1;
    const int w_c = w & 1;
    const int sbase = blockIdx.y * 64;
    const int fbase = blockIdx.x * 64;

    const int srow = t >> 2;
    const int skseg = (t & 3) * 8;

    f32x4 acc[2][2];
#pragma unroll
    for (int m = 0; m < 2; ++m)
#pragma unroll
        for (int n = 0; n < 2; ++n) acc[m][n] = (f32x4){0.f, 0.f, 0.f, 0.f};

    const int lr = lane & 15;
    const int lk = (lane >> 4) * 8;

    {
        *(half8*)&As[0][srow][skseg] = *(const half8*)&A [(size_t)(sbase + srow) * 1024 + skseg];
        *(half8*)&Bs[0][srow][skseg] = *(const half8*)&Bt[(size_t)(fbase + srow) * 1024 + skseg];
    }
    __syncthreads();

    for (int tile = 0; tile < 32; ++tile) {
        const int cur = tile & 1;
        if (tile < 31) {
            const int kb = (tile + 1) * 32;
            half8 av = *(const half8*)&A [(size_t)(sbase + srow) * 1024 + kb + skseg];
            half8 bv = *(const half8*)&Bt[(size_t)(fbase + srow) * 1024 + kb + skseg];
            *(half8*)&As[cur ^ 1][srow][skseg] = av;
            *(half8*)&Bs[cur ^ 1][srow][skseg] = bv;
        }
        half8 a0 = *(const half8*)&As[cur][w_r * 32 + 0  + lr][lk];
        half8 a1 = *(const half8*)&As[cur][w_r * 32 + 16 + lr][lk];
        half8 b0 = *(const half8*)&Bs[cur][w_c * 32 + 0  + lr][lk];
        half8 b1 = *(const half8*)&Bs[cur][w_c * 32 + 16 + lr][lk];
        acc[0][0] = __builtin_amdgcn_mfma_f32_16x16x32_f16(a0, b0, acc[0][0], 0, 0, 0);
        acc[0][1] = __builtin_amdgcn_mfma_f32_16x16x32_f16(a0, b1, acc[0][1], 0, 0, 0);
        acc[1][0] = __builtin_amdgcn_mfma_f32_16x16x32_f16(a1, b0, acc[1][0], 0, 0, 0);
        acc[1][1] = __builtin_amdgcn_mfma_f32_16x16x32_f16(a1, b1, acc[1][1], 0, 0, 0);
        __syncthreads();
    }

#pragma unroll
    for (int m = 0; m < 2; ++m) {
        const int row0 = sbase + w_r * 32 + m * 16 + (lane >> 4) * 4;
#pragma unroll
        for (int n = 0; n < 2; ++n) {
            const int col = fbase + w_c * 32 + n * 16 + (lane & 15);
            const float bval = bias[col];
            if (MODE == 0) {
                float* O = (float*)Op;
#pragma unroll
                for (int r = 0; r < 4; ++r)
                    O[(size_t)(row0 + r) * 1024 + col] = acc[m][n][r] + bval;
            } else {
                _Float16* O = (_Float16*)Op;
                const int hh = col >> 6;
                const int d = col & 63;
                if (z == 2) {   // V transposed: O[h][d][s]
                    half4 o;
#pragma unroll
                    for (int r = 0; r < 4; ++r) o[r] = (_Float16)(acc[m][n][r] + bval);
                    *(half4*)&O[((size_t)hh << 16) + (size_t)d * 1024 + row0] = o;
                } else {        // Q/K: O[h][s][d]
#pragma unroll
                    for (int r = 0; r < 4; ++r)
                        O[((size_t)hh << 16) + (size_t)(row0 + r) * 64 + d] =
                            (_Float16)(acc[m][n][r] + bval);
                }
            }
        }
    }
}

// ---------------------------------------------------------------------------
// Fused attention, occupancy-optimized.
// Block = (head h, 16 q-rows). 4 waves split the 1024-k range (256 k each),
// running barrier-free: K/V fragments loaded straight from global (L2-hot).
// Phase A: per-(q,wl) partial denominators -> shfl + LDS cross-wave reduce.
// Phase B: P_sum = sum_wl wgt*exp2(c*s) -> f16 -> PV MFMA partials -> LDS
// reduce -> comb f16.
// ---------------------------------------------------------------------------
__global__ __launch_bounds__(256, 4)
void attn_k(const _Float16* __restrict__ Qg, const _Float16* __restrict__ Kg,
            const _Float16* __restrict__ Vg, const float* __restrict__ pm,
            const float* __restrict__ iwp, _Float16* __restrict__ comb)
{
    const int h  = blockIdx.y;
    const int qt = blockIdx.x;          // 64 tiles of 16 q rows
    const int t = threadIdx.x;
    const int lane = t & 63;
    const int w = t >> 6;               // wave id = k-quarter
    const int lr = lane & 15;
    const int lg = lane >> 4;

    __shared__ float Sred[4][16][68];   // den partials, then O partials
    __shared__ _Float16 Ps[4][16][72];  // per-wave P chunk [q][k64]
    __shared__ float sc[16], siw[16];

    if (t < 16) {
        float m = cosf(pm[t * NH + h]);
        sc[t] = m * m * 0.125f * 1.44269504f;   // c * log2(e)
        siw[t] = iwp[t];
    }

    // Q fragments (B-operand): row = q-local = lr, k-seg = lg*8
    const _Float16* Qrow = Qg + ((size_t)h << 16) + (size_t)(qt * 16 + lr) * 64;
    half8 q0 = *(const half8*)&Qrow[lg * 8];
    half8 q1 = *(const half8*)&Qrow[32 + lg * 8];
    __syncthreads();

    float c2[16];
#pragma unroll
    for (int i = 0; i < NWL; ++i) c2[i] = sc[i];

    const _Float16* Kq = Kg + ((size_t)h << 16) + (size_t)w * 256 * 64;  // wave's k-quarter
    const _Float16* Vh = Vg + ((size_t)h << 16);                         // V^T [d][s]

    // ---- Phase A: partial denominators over this wave's 256 k ----
    float den[16];
#pragma unroll
    for (int i = 0; i < NWL; ++i) den[i] = 0.f;

    for (int ch = 0; ch < 4; ++ch) {
#pragma unroll
        for (int kf = 0; kf < 4; ++kf) {
            const _Float16* Kr = Kq + (size_t)(ch * 64 + kf * 16 + lr) * 64;
            half8 a0 = *(const half8*)&Kr[lg * 8];
            half8 a1 = *(const half8*)&Kr[32 + lg * 8];
            f32x4 s2 = (f32x4){0.f, 0.f, 0.f, 0.f};
            s2 = __builtin_amdgcn_mfma_f32_16x16x32_f16(a0, q0, s2, 0, 0, 0);
            s2 = __builtin_amdgcn_mfma_f32_16x16x32_f16(a1, q1, s2, 0, 0, 0);
#pragma unroll
            for (int r = 0; r < 4; ++r) {
                const float sv = s2[r];
#pragma unroll
                for (int i = 0; i < NWL; ++i)
                    den[i] += exp2f(c2[i] * sv);
            }
        }
    }

    // sum over the 4 lane-groups (k bits) -> lanes hold quarter-sum for q=lr
#pragma unroll
    for (int off = 16; off < 64; off <<= 1)
#pragma unroll
        for (int i = 0; i < NWL; ++i)
            den[i] += __shfl_xor(den[i], off);

    if (lg == 0) {
#pragma unroll
        for (int i = 0; i < NWL; ++i) Sred[w][lr][i] = den[i];
    }
    __syncthreads();

    float wgt[16];
#pragma unroll
    for (int i = 0; i < NWL; ++i) {
        const float d4 = Sred[0][lr][i] + Sred[1][lr][i] + Sred[2][lr][i] + Sred[3][lr][i];
        wgt[i] = siw[i] / (d4 * 16.0f);
    }
    __syncthreads();   // Sred reuse as O-partials below

    // ---- Phase B: P_sum chunks + PV partials over this wave's 256 k ----
    f32x4 oacc[4];
#pragma unroll
    for (int n = 0; n < 4; ++n) oacc[n] = (f32x4){0.f, 0.f, 0.f, 0.f};

    for (int ch = 0; ch < 4; ++ch) {
#pragma unroll
        for (int kf = 0; kf < 4; ++kf) {
            const _Float16* Kr = Kq + (size_t)(ch * 64 + kf * 16 + lr) * 64;
            half8 a0 = *(const half8*)&Kr[lg * 8];
            half8 a1 = *(const half8*)&Kr[32 + lg * 8];
            f32x4 s2 = (f32x4){0.f, 0.f, 0.f, 0.f};
            s2 = __builtin_amdgcn_mfma_f32_16x16x32_f16(a0, q0, s2, 0, 0, 0);
            s2 = __builtin_amdgcn_mfma_f32_16x16x32_f16(a1, q1, s2, 0, 0, 0);
            half4 ph;
#pragma unroll
            for (int r = 0; r < 4; ++r) {
                const float sv = s2[r];
                float p = 0.f;
#pragma unroll
                for (int i = 0; i < NWL; ++i)
                    p = fmaf(wgt[i], exp2f(c2[i] * sv), p);
                ph[r] = (_Float16)p;
            }
            // P[q=lr][k-local = kf*16 + lg*4 + r], per-wave private buffer
            *(half4*)&Ps[w][lr][kf * 16 + lg * 4] = ph;
        }
        // same-wave LDS dep; compiler inserts lgkm waits
        half8 pa0 = *(const half8*)&Ps[w][lr][lg * 8];
        half8 pa1 = *(const half8*)&Ps[w][lr][32 + lg * 8];
        const int kcol = w * 256 + ch * 64;
#pragma unroll
        for (int n = 0; n < 4; ++n) {
            const _Float16* Vr = Vh + (size_t)(n * 16 + lr) * 1024 + kcol;
            half8 vb0 = *(const half8*)&Vr[lg * 8];
            half8 vb1 = *(const half8*)&Vr[32 + lg * 8];
            oacc[n] = __builtin_amdgcn_mfma_f32_16x16x32_f16(pa0, vb0, oacc[n], 0, 0, 0);
            oacc[n] = __builtin_amdgcn_mfma_f32_16x16x32_f16(pa1, vb1, oacc[n], 0, 0, 0);
        }
    }

    // write per-wave O partials: O[q = lg*4+r][d = n*16+lr]
#pragma unroll
    for (int n = 0; n < 4; ++n)
#pragma unroll
        for (int r = 0; r < 4; ++r)
            Sred[w][lg * 4 + r][n * 16 + lr] = oacc[n][r];
    __syncthreads();

    // final cross-wave reduce: thread t -> q = t>>4, d0 = (t&15)*4
    {
        const int q = t >> 4;
        const int d0 = (t & 15) * 4;
        f32x4 s0 = *(const f32x4*)&Sred[0][q][d0];
        f32x4 s1 = *(const f32x4*)&Sred[1][q][d0];
        f32x4 s2v = *(const f32x4*)&Sred[2][q][d0];
        f32x4 s3 = *(const f32x4*)&Sred[3][q][d0];
        f32x4 sum = s0 + s1 + s2v + s3;
        half4 o;
#pragma unroll
        for (int r = 0; r < 4; ++r) o[r] = (_Float16)sum[r];
        *(half4*)&comb[(size_t)(qt * 16 + q) * 1024 + h * 64 + d0] = o;
    }
}

// ---------------------------------------------------------------------------
extern "C" void kernel_launch(void* const* d_in, const int* in_sizes, int n_in,
                              void* d_out, int out_size, void* d_ws, size_t ws_size,
                              hipStream_t stream)
{
    const float* x  = (const float*)d_in[0];
    const float* Wq = (const float*)d_in[1];
    const float* bq = (const float*)d_in[2];
    const float* Wk = (const float*)d_in[3];
    const float* bk = (const float*)d_in[4];
    const float* Wv = (const float*)d_in[5];
    const float* bv = (const float*)d_in[6];
    const float* Wo = (const float*)d_in[7];
    const float* bo = (const float*)d_in[8];
    const float* pm = (const float*)d_in[9];
    const float* iw = (const float*)d_in[10];
    float* out = (float*)d_out;

    // ws (f16 elems): Xh 1M (reused as comb) | WT 4M | Q 1M | K 1M | Vt 1M = 16 MB
    _Float16* Xh = (_Float16*)d_ws;
    _Float16* WT = Xh + (1u << 20);
    _Float16* Qh = WT + (4u << 20);
    _Float16* Kh = Qh + (1u << 20);
    _Float16* Vt = Kh + (1u << 20);
    _Float16* comb = Xh;   // Xh dead after QKV GEMM

    dim3 blk(256);
    cast_x_k<<<dim3(512), blk, 0, stream>>>(x, Xh);
    castT_w<<<dim3(16, 16, 4), blk, 0, stream>>>(Wq, Wk, Wv, Wo, WT);
    gemm_mfma<1><<<dim3(16, 16, 3), blk, 0, stream>>>(Xh, WT, bq, bk, bv, Qh, Kh, Vt);
    attn_k<<<dim3(64, 16), blk, 0, stream>>>(Qh, Kh, Vt, pm, iw, comb);
    gemm_mfma<0><<<dim3(16, 16, 1), blk, 0, stream>>>(
        comb, WT + (3u << 20), bo, bo, bo, out, out, out);
}

// Round 5
// 100.819 us; speedup vs baseline: 2.1050x; 2.1050x over previous
//
#include <hip/hip_runtime.h>
#include <hip/hip_fp16.h>
#include <math.h>

#define NH 16
#define NWL 16
#define NPOLY 10   // Taylor degree for residual exp; |γ·s|<=~1.2 -> rel err ~1e-7

typedef _Float16 half8 __attribute__((ext_vector_type(8)));
typedef _Float16 half4 __attribute__((ext_vector_type(4)));
typedef float f32x4 __attribute__((ext_vector_type(4)));

// ---------------------------------------------------------------------------
// cast x (fp32 -> f16), 8 elems/thread
// ---------------------------------------------------------------------------
__global__ __launch_bounds__(256)
void cast_x_k(const float* __restrict__ X, _Float16* __restrict__ Xh)
{
    const int i = (blockIdx.x * 256 + threadIdx.x) * 8;
    float4 v0 = *(const float4*)&X[i];
    float4 v1 = *(const float4*)&X[i + 4];
    half8 o;
    o[0] = (_Float16)v0.x; o[1] = (_Float16)v0.y; o[2] = (_Float16)v0.z; o[3] = (_Float16)v0.w;
    o[4] = (_Float16)v1.x; o[5] = (_Float16)v1.y; o[6] = (_Float16)v1.z; o[7] = (_Float16)v1.w;
    *(half8*)&Xh[i] = o;
}

// ---------------------------------------------------------------------------
// cast + transpose W[e][f] -> WT[f][e] f16, 64x64 tiles, z picks which W
// ---------------------------------------------------------------------------
__global__ __launch_bounds__(256)
void castT_w(const float* __restrict__ W0, const float* __restrict__ W1,
             const float* __restrict__ W2, const float* __restrict__ W3,
             _Float16* __restrict__ WT)
{
    const float* W = W0;
    if (blockIdx.z == 1) W = W1;
    if (blockIdx.z == 2) W = W2;
    if (blockIdx.z == 3) W = W3;
    _Float16* out = WT + ((size_t)blockIdx.z << 20);

    __shared__ float Ts[64][65];
    const int t = threadIdx.x;
    const int ebase = blockIdx.y * 64;
    const int fbase = blockIdx.x * 64;

    {
        const int r0 = (t >> 4) * 4;
        const int c0 = (t & 15) * 4;
#pragma unroll
        for (int r = 0; r < 4; ++r) {
            float4 v = *(const float4*)&W[(size_t)(ebase + r0 + r) * 1024 + fbase + c0];
            Ts[r0 + r][c0 + 0] = v.x;
            Ts[r0 + r][c0 + 1] = v.y;
            Ts[r0 + r][c0 + 2] = v.z;
            Ts[r0 + r][c0 + 3] = v.w;
        }
    }
    __syncthreads();

    const int f = t >> 2;
    const int eseg = (t & 3) * 16;
    half8 lo, hi;
#pragma unroll
    for (int j = 0; j < 8; ++j) lo[j] = (_Float16)Ts[eseg + j][f];
#pragma unroll
    for (int j = 0; j < 8; ++j) hi[j] = (_Float16)Ts[eseg + 8 + j][f];
    *(half8*)&out[(size_t)(fbase + f) * 1024 + ebase + eseg]     = lo;
    *(half8*)&out[(size_t)(fbase + f) * 1024 + ebase + eseg + 8] = hi;
}

// ---------------------------------------------------------------------------
// MFMA GEMM (f16): C[s][f] = sum_e A[s][e]*W[e][f] + bias[f]
// 64x64 tile, BK=32, 4 waves (2x2), 16x16x32_f16 frags, double-buffered LDS.
// MODE 0: fp32 out[s][f]
// MODE 1: f16 head-split: z=0,1 -> O[h][s][d]; z=2 -> transposed O[h][d][s]
// ---------------------------------------------------------------------------
template<int MODE>
__global__ __launch_bounds__(256)
void gemm_mfma(const _Float16* __restrict__ A,
               const _Float16* __restrict__ BtBase,
               const float* __restrict__ B0, const float* __restrict__ B1,
               const float* __restrict__ B2,
               void* __restrict__ O0p, void* __restrict__ O1p, void* __restrict__ O2p)
{
    const int z = blockIdx.z;
    const _Float16* Bt = BtBase + ((size_t)z << 20);
    const float* bias = B0; void* Op = O0p;
    if (z == 1) { bias = B1; Op = O1p; }
    if (z == 2) { bias = B2; Op = O2p; }

    __shared__ _Float16 As[2][64][40];
    __shared__ _Float16 Bs[2][64][40];

    const int t = threadIdx.x;
    const int lane = t & 63;
    const int w = t >> 6;
    const int w_r = w >> 1;
    const int w_c = w & 1;
    const int sbase = blockIdx.y * 64;
    const int fbase = blockIdx.x * 64;

    const int srow = t >> 2;
    const int skseg = (t & 3) * 8;

    f32x4 acc[2][2];
#pragma unroll
    for (int m = 0; m < 2; ++m)
#pragma unroll
        for (int n = 0; n < 2; ++n) acc[m][n] = (f32x4){0.f, 0.f, 0.f, 0.f};

    const int lr = lane & 15;
    const int lk = (lane >> 4) * 8;

    {
        *(half8*)&As[0][srow][skseg] = *(const half8*)&A [(size_t)(sbase + srow) * 1024 + skseg];
        *(half8*)&Bs[0][srow][skseg] = *(const half8*)&Bt[(size_t)(fbase + srow) * 1024 + skseg];
    }
    __syncthreads();

    for (int tile = 0; tile < 32; ++tile) {
        const int cur = tile & 1;
        if (tile < 31) {
            const int kb = (tile + 1) * 32;
            half8 av = *(const half8*)&A [(size_t)(sbase + srow) * 1024 + kb + skseg];
            half8 bv = *(const half8*)&Bt[(size_t)(fbase + srow) * 1024 + kb + skseg];
            *(half8*)&As[cur ^ 1][srow][skseg] = av;
            *(half8*)&Bs[cur ^ 1][srow][skseg] = bv;
        }
        half8 a0 = *(const half8*)&As[cur][w_r * 32 + 0  + lr][lk];
        half8 a1 = *(const half8*)&As[cur][w_r * 32 + 16 + lr][lk];
        half8 b0 = *(const half8*)&Bs[cur][w_c * 32 + 0  + lr][lk];
        half8 b1 = *(const half8*)&Bs[cur][w_c * 32 + 16 + lr][lk];
        acc[0][0] = __builtin_amdgcn_mfma_f32_16x16x32_f16(a0, b0, acc[0][0], 0, 0, 0);
        acc[0][1] = __builtin_amdgcn_mfma_f32_16x16x32_f16(a0, b1, acc[0][1], 0, 0, 0);
        acc[1][0] = __builtin_amdgcn_mfma_f32_16x16x32_f16(a1, b0, acc[1][0], 0, 0, 0);
        acc[1][1] = __builtin_amdgcn_mfma_f32_16x16x32_f16(a1, b1, acc[1][1], 0, 0, 0);
        __syncthreads();
    }

#pragma unroll
    for (int m = 0; m < 2; ++m) {
        const int row0 = sbase + w_r * 32 + m * 16 + (lane >> 4) * 4;
#pragma unroll
        for (int n = 0; n < 2; ++n) {
            const int col = fbase + w_c * 32 + n * 16 + (lane & 15);
            const float bval = bias[col];
            if (MODE == 0) {
                float* O = (float*)Op;
#pragma unroll
                for (int r = 0; r < 4; ++r)
                    O[(size_t)(row0 + r) * 1024 + col] = acc[m][n][r] + bval;
            } else {
                _Float16* O = (_Float16*)Op;
                const int hh = col >> 6;
                const int d = col & 63;
                if (z == 2) {   // V transposed: O[h][d][s]
                    half4 o;
#pragma unroll
                    for (int r = 0; r < 4; ++r) o[r] = (_Float16)(acc[m][n][r] + bval);
                    *(half4*)&O[((size_t)hh << 16) + (size_t)d * 1024 + row0] = o;
                } else {        // Q/K: O[h][s][d]
#pragma unroll
                    for (int r = 0; r < 4; ++r)
                        O[((size_t)hh << 16) + (size_t)(row0 + r) * 64 + d] =
                            (_Float16)(acc[m][n][r] + bval);
                }
            }
        }
    }
}

// ---------------------------------------------------------------------------
// Fused attention, moment/poly form.
//   sum_i w_i 2^{a_i s} = 2^{abar s} * sum_i w_i e^{g_i s},  g_i=(a_i-abar)ln2
// Phase A accumulates channel-independent moments M_n = sum_k s^n 2^{abar s};
// den_i = sum_n (g_i^n/n!) M_n. Phase B: P(s) = 2^{abar s}*Horner(s; c_n),
// c_n = sum_i wgt_i g_i^n/n!  (per q-row). |g_i s| <= ~1.2 -> deg-10 exact
// to ~1e-7 rel. Replaces 16 exp/entry with 1 exp + ~11 fma (4x less VALU).
// Block = (head, 16 q rows), 4 waves split k (256 each), barrier-free k-loop.
// XCD swizzle: 2 heads per XCD -> K/V L2-resident.
// ---------------------------------------------------------------------------
__global__ __launch_bounds__(256, 4)
void attn_k(const _Float16* __restrict__ Qg, const _Float16* __restrict__ Kg,
            const _Float16* __restrict__ Vg, const float* __restrict__ pm,
            const float* __restrict__ iwp, _Float16* __restrict__ comb)
{
    // XCD-aware remap: consecutive blockIdx round-robin across 8 XCDs;
    // give each XCD 2 contiguous heads so K+V (512KB) sits in its L2.
    const int wg  = blockIdx.x;
    const int xcd = wg & 7;
    const int idx = wg >> 3;            // 0..127
    const int h   = xcd * 2 + (idx >> 6);
    const int qt  = idx & 63;           // 16-row q tile

    const int t = threadIdx.x;
    const int lane = t & 63;
    const int w = t >> 6;               // wave id = k-quarter
    const int lr = lane & 15;
    const int lg = lane >> 4;

    __shared__ float Sred[4][16][68];   // moment partials, then O partials
    __shared__ _Float16 Ps[4][16][72];  // per-wave P chunk [q][k64]
    __shared__ float sa[16], siw[16];
    __shared__ float gt[16][NPOLY + 1]; // g_i^n / n!

    if (t < 16) {
        float m = cosf(pm[t * NH + h]);
        sa[t] = m * m * 0.125f * 1.44269504f;   // a_i (log2 scale)
        siw[t] = iwp[t];
    }
    __syncthreads();

    // every lane: abar = (max+min)/2 over channels
    float amin = sa[0], amax = sa[0];
#pragma unroll
    for (int i = 1; i < NWL; ++i) {
        amin = fminf(amin, sa[i]);
        amax = fmaxf(amax, sa[i]);
    }
    const float abar = 0.5f * (amin + amax);

    if (t < 16) {
        float g = (sa[t] - abar) * 0.69314718f;  // natural-log residual
        float p = 1.f;
        gt[t][0] = 1.f;
#pragma unroll
        for (int n = 1; n <= NPOLY; ++n) {
            p *= g / (float)n;
            gt[t][n] = p;
        }
    }

    // Q fragments (B-operand): row = q-local = lr, k-seg = lg*8
    const _Float16* Qrow = Qg + ((size_t)h << 16) + (size_t)(qt * 16 + lr) * 64;
    half8 q0 = *(const half8*)&Qrow[lg * 8];
    half8 q1 = *(const half8*)&Qrow[32 + lg * 8];
    __syncthreads();

    const _Float16* Kq = Kg + ((size_t)h << 16) + (size_t)w * 256 * 64;  // wave's k-quarter
    const _Float16* Vh = Vg + ((size_t)h << 16);                         // V^T [d][s]

    // ---- Phase A: moments over this wave's 256 k ----
    float M[NPOLY + 1];
#pragma unroll
    for (int n = 0; n <= NPOLY; ++n) M[n] = 0.f;

    for (int ch = 0; ch < 4; ++ch) {
#pragma unroll
        for (int kf = 0; kf < 4; ++kf) {
            const _Float16* Kr = Kq + (size_t)(ch * 64 + kf * 16 + lr) * 64;
            half8 a0 = *(const half8*)&Kr[lg * 8];
            half8 a1 = *(const half8*)&Kr[32 + lg * 8];
            f32x4 s2 = (f32x4){0.f, 0.f, 0.f, 0.f};
            s2 = __builtin_amdgcn_mfma_f32_16x16x32_f16(a0, q0, s2, 0, 0, 0);
            s2 = __builtin_amdgcn_mfma_f32_16x16x32_f16(a1, q1, s2, 0, 0, 0);
#pragma unroll
            for (int r = 0; r < 4; ++r) {
                const float sv = s2[r];
                float e = exp2f(abar * sv);
                M[0] += e;
#pragma unroll
                for (int n = 1; n <= NPOLY; ++n) {
                    e *= sv;
                    M[n] += e;
                }
            }
        }
    }

    // sum over the 4 lane-groups (k bits) -> per-q quarter moments
#pragma unroll
    for (int off = 16; off < 64; off <<= 1)
#pragma unroll
        for (int n = 0; n <= NPOLY; ++n)
            M[n] += __shfl_xor(M[n], off);

    if (lg == 0) {
#pragma unroll
        for (int n = 0; n <= NPOLY; ++n) Sred[w][lr][n] = M[n];
    }
    __syncthreads();

#pragma unroll
    for (int n = 0; n <= NPOLY; ++n)
        M[n] = Sred[0][lr][n] + Sred[1][lr][n] + Sred[2][lr][n] + Sred[3][lr][n];

    // den_i = sum_n gt[i][n] * M[n];  wgt_i = iw_i/(16 den_i);
    // c_n = sum_i wgt_i gt[i][n]
    float c[NPOLY + 1];
#pragma unroll
    for (int n = 0; n <= NPOLY; ++n) c[n] = 0.f;
#pragma unroll
    for (int i = 0; i < NWL; ++i) {
        float den = 0.f;
#pragma unroll
        for (int n = 0; n <= NPOLY; ++n) den = fmaf(gt[i][n], M[n], den);
        const float wgt = siw[i] / (den * 16.0f);
#pragma unroll
        for (int n = 0; n <= NPOLY; ++n) c[n] = fmaf(wgt, gt[i][n], c[n]);
    }
    __syncthreads();   // all M reads done; Sred reused as O-partials below

    // ---- Phase B: P chunks + PV partials over this wave's 256 k ----
    f32x4 oacc[4];
#pragma unroll
    for (int n = 0; n < 4; ++n) oacc[n] = (f32x4){0.f, 0.f, 0.f, 0.f};

    for (int ch = 0; ch < 4; ++ch) {
#pragma unroll
        for (int kf = 0; kf < 4; ++kf) {
            const _Float16* Kr = Kq + (size_t)(ch * 64 + kf * 16 + lr) * 64;
            half8 a0 = *(const half8*)&Kr[lg * 8];
            half8 a1 = *(const half8*)&Kr[32 + lg * 8];
            f32x4 s2 = (f32x4){0.f, 0.f, 0.f, 0.f};
            s2 = __builtin_amdgcn_mfma_f32_16x16x32_f16(a0, q0, s2, 0, 0, 0);
            s2 = __builtin_amdgcn_mfma_f32_16x16x32_f16(a1, q1, s2, 0, 0, 0);
            half4 ph;
#pragma unroll
            for (int r = 0; r < 4; ++r) {
                const float sv = s2[r];
                const float e = exp2f(abar * sv);
                float poly = c[NPOLY];
#pragma unroll
                for (int n = NPOLY - 1; n >= 0; --n)
                    poly = fmaf(poly, sv, c[n]);
                ph[r] = (_Float16)(e * poly);
            }
            // P[q=lr][k-local = kf*16 + lg*4 + r], per-wave private buffer
            *(half4*)&Ps[w][lr][kf * 16 + lg * 4] = ph;
        }
        // same-wave LDS dep; compiler inserts lgkm waits
        half8 pa0 = *(const half8*)&Ps[w][lr][lg * 8];
        half8 pa1 = *(const half8*)&Ps[w][lr][32 + lg * 8];
        const int kcol = w * 256 + ch * 64;
#pragma unroll
        for (int n = 0; n < 4; ++n) {
            const _Float16* Vr = Vh + (size_t)(n * 16 + lr) * 1024 + kcol;
            half8 vb0 = *(const half8*)&Vr[lg * 8];
            half8 vb1 = *(const half8*)&Vr[32 + lg * 8];
            oacc[n] = __builtin_amdgcn_mfma_f32_16x16x32_f16(pa0, vb0, oacc[n], 0, 0, 0);
            oacc[n] = __builtin_amdgcn_mfma_f32_16x16x32_f16(pa1, vb1, oacc[n], 0, 0, 0);
        }
    }

    // write per-wave O partials: O[q = lg*4+r][d = n*16+lr]
#pragma unroll
    for (int n = 0; n < 4; ++n)
#pragma unroll
        for (int r = 0; r < 4; ++r)
            Sred[w][lg * 4 + r][n * 16 + lr] = oacc[n][r];
    __syncthreads();

    // final cross-wave reduce: thread t -> q = t>>4, d0 = (t&15)*4
    {
        const int q = t >> 4;
        const int d0 = (t & 15) * 4;
        f32x4 s0 = *(const f32x4*)&Sred[0][q][d0];
        f32x4 s1 = *(const f32x4*)&Sred[1][q][d0];
        f32x4 s2v = *(const f32x4*)&Sred[2][q][d0];
        f32x4 s3 = *(const f32x4*)&Sred[3][q][d0];
        f32x4 sum = s0 + s1 + s2v + s3;
        half4 o;
#pragma unroll
        for (int r = 0; r < 4; ++r) o[r] = (_Float16)sum[r];
        *(half4*)&comb[(size_t)(qt * 16 + q) * 1024 + h * 64 + d0] = o;
    }
}

// ---------------------------------------------------------------------------
extern "C" void kernel_launch(void* const* d_in, const int* in_sizes, int n_in,
                              void* d_out, int out_size, void* d_ws, size_t ws_size,
                              hipStream_t stream)
{
    const float* x  = (const float*)d_in[0];
    const float* Wq = (const float*)d_in[1];
    const float* bq = (const float*)d_in[2];
    const float* Wk = (const float*)d_in[3];
    const float* bk = (const float*)d_in[4];
    const float* Wv = (const float*)d_in[5];
    const float* bv = (const float*)d_in[6];
    const float* Wo = (const float*)d_in[7];
    const float* bo = (const float*)d_in[8];
    const float* pm = (const float*)d_in[9];
    const float* iw = (const float*)d_in[10];
    float* out = (float*)d_out;

    // ws (f16 elems): Xh 1M (reused as comb) | WT 4M | Q 1M | K 1M | Vt 1M = 16 MB
    _Float16* Xh = (_Float16*)d_ws;
    _Float16* WT = Xh + (1u << 20);
    _Float16* Qh = WT + (4u << 20);
    _Float16* Kh = Qh + (1u << 20);
    _Float16* Vt = Kh + (1u << 20);
    _Float16* comb = Xh;   // Xh dead after QKV GEMM

    dim3 blk(256);
    cast_x_k<<<dim3(512), blk, 0, stream>>>(x, Xh);
    castT_w<<<dim3(16, 16, 4), blk, 0, stream>>>(Wq, Wk, Wv, Wo, WT);
    gemm_mfma<1><<<dim3(16, 16, 3), blk, 0, stream>>>(Xh, WT, bq, bk, bv, Qh, Kh, Vt);
    attn_k<<<dim3(1024), blk, 0, stream>>>(Qh, Kh, Vt, pm, iw, comb);
    gemm_mfma<0><<<dim3(16, 16, 1), blk, 0, stream>>>(
        comb, WT + (3u << 20), bo, bo, bo, out, out, out);
}